// Round 2
// baseline (261.788 us; speedup 1.0000x reference)
//
#include <hip/hip_runtime.h>
#include <hip/hip_bf16.h>
#include <math.h>

typedef short bf16x8 __attribute__((ext_vector_type(8)));
typedef float f32x4 __attribute__((ext_vector_type(4)));

#define MFMA16x16(a, b, c) __builtin_amdgcn_mfma_f32_16x16x32_bf16(a, b, c, 0, 0, 0)

__device__ __forceinline__ float silu_f(float v) { return v / (1.0f + __expf(-v)); }
// XOR swizzle for [row][128B] LDS tiles: kills the 16/32-way bank conflict on ds_read_b128
__device__ __forceinline__ int swz128(int b) { return b ^ (((b >> 7) & 7) << 4); }

__device__ __forceinline__ unsigned short f2bf(float f) {  // RNE f32->bf16
  union { float f; unsigned u; } x; x.f = f;
  unsigned r = x.u + 0x7fffu + ((x.u >> 16) & 1u);
  return (unsigned short)(r >> 16);
}
__device__ __forceinline__ float bf2f(unsigned short h) {
  union { unsigned u; float f; } x; x.u = ((unsigned)h) << 16;
  return x.f;
}

__device__ __forceinline__ void gload_lds16(const void* g, void* l) {
  __builtin_amdgcn_global_load_lds((__attribute__((address_space(1))) unsigned int*)g,
                                   (__attribute__((address_space(3))) unsigned int*)l,
                                   16, 0, 0);
}

// ---------- offsets prep: tolerate int64 or int32 storage ----------
__global__ void k_prep_offs(const int* __restrict__ raw, int* __restrict__ offs, int Bp1) {
  int t = threadIdx.x;
  bool is64 = (raw[3] == 0);
  if (t < Bp1) offs[t] = is64 ? raw[2 * t] : raw[t];
}

// ---------- uvqk (512x2048 f32) -> uvqkT (2048x512 bf16), transposed ----------
__global__ __launch_bounds__(256) void k_conv_uvqkT(const float* __restrict__ uvqk,
                                                    unsigned short* __restrict__ uvqkT) {
  __shared__ float tile[32][33];
  int n0 = blockIdx.x * 32, k0 = blockIdx.y * 32;
  int tx = threadIdx.x & 31;
  int ty = threadIdx.x >> 5;  // 0..7
#pragma unroll
  for (int i = 0; i < 4; ++i)
    tile[ty + 8 * i][tx] = uvqk[(size_t)(k0 + ty + 8 * i) * 2048 + n0 + tx];
  __syncthreads();
#pragma unroll
  for (int i = 0; i < 4; ++i) {
    int nn = ty + 8 * i;
    uvqkT[(size_t)(n0 + nn) * 512 + k0 + tx] = f2bf(tile[tx][nn]);
  }
}

__global__ __launch_bounds__(256) void k_conv_bf16(const float* __restrict__ in,
                                                   unsigned short* __restrict__ out, int n) {
  int i = blockIdx.x * 256 + threadIdx.x;
  if (i < n) out[i] = f2bf(in[i]);
}

// ---------- LayerNorm(x) -> bf16, one wave per 512-row ----------
__global__ __launch_bounds__(256) void k_ln_x(const float* __restrict__ x,
                                              unsigned short* __restrict__ normed, int T) {
  int lane = threadIdx.x & 63, wid = threadIdx.x >> 6;
  int row = blockIdx.x * 4 + wid;
  if (row >= T) return;
  const float4* xr = (const float4*)(x + (size_t)row * 512);
  float4 a = xr[lane * 2], b = xr[lane * 2 + 1];
  float s = a.x + a.y + a.z + a.w + b.x + b.y + b.z + b.w;
  float s2 = a.x * a.x + a.y * a.y + a.z * a.z + a.w * a.w +
             b.x * b.x + b.y * b.y + b.z * b.z + b.w * b.w;
#pragma unroll
  for (int m = 1; m < 64; m <<= 1) { s += __shfl_xor(s, m); s2 += __shfl_xor(s2, m); }
  float mean = s * (1.0f / 512.0f);
  float var = s2 * (1.0f / 512.0f) - mean * mean;
  float rstd = rsqrtf(var + 1e-6f);
  float v[8] = {a.x, a.y, a.z, a.w, b.x, b.y, b.z, b.w};
  unsigned short o[8];
#pragma unroll
  for (int j = 0; j < 8; ++j) o[j] = f2bf((v[j] - mean) * rstd);
  *(uint4*)(normed + (size_t)row * 512 + lane * 8) = *(uint4*)o;
}

// ---------- o_input = u * LayerNorm(attn_bf16) -> bf16 ----------
__global__ __launch_bounds__(256) void k_ln_mul_u(const unsigned short* __restrict__ attnb,
                                                  const unsigned short* __restrict__ mm,
                                                  unsigned short* __restrict__ oin, int T) {
  int lane = threadIdx.x & 63, wid = threadIdx.x >> 6;
  int row = blockIdx.x * 4 + wid;
  if (row >= T) return;
  uint4 av = *(const uint4*)(attnb + (size_t)row * 512 + lane * 8);
  const unsigned short* ae = (const unsigned short*)&av;
  float v[8];
#pragma unroll
  for (int j = 0; j < 8; ++j) v[j] = bf2f(ae[j]);
  float s = 0.f, s2 = 0.f;
#pragma unroll
  for (int j = 0; j < 8; ++j) { s += v[j]; s2 += v[j] * v[j]; }
#pragma unroll
  for (int m = 1; m < 64; m <<= 1) { s += __shfl_xor(s, m); s2 += __shfl_xor(s2, m); }
  float mean = s * (1.0f / 512.0f);
  float var = s2 * (1.0f / 512.0f) - mean * mean;
  float rstd = rsqrtf(var + 1e-6f);
  uint4 ub = *(const uint4*)(mm + (size_t)row * 2048 + lane * 8);  // u = mm[:, 0:512]
  const unsigned short* us = (const unsigned short*)&ub;
  unsigned short o[8];
#pragma unroll
  for (int j = 0; j < 8; ++j) o[j] = f2bf((v[j] - mean) * rstd * bf2f(us[j]));
  *(uint4*)(oin + (size_t)row * 512 + lane * 8) = *(uint4*)o;
}

// ---------- MFMA GEMM, 128x128 tile, BK=64, Bt is (N,K) row-major ----------
// MODE 0: C = silu(A@Bt^T) -> bf16 ; MODE 1: C = A@Bt^T + bias + xres -> f32
template <int MODE>
__global__ __launch_bounds__(256) void k_gemm_bt(const unsigned short* __restrict__ A,
                                                 const unsigned short* __restrict__ Bt,
                                                 void* __restrict__ Cout,
                                                 const float* __restrict__ bias,
                                                 const float* __restrict__ xres,
                                                 int M, int Nn, int K, int ntn) {
  __shared__ __align__(16) char lds[32768];
  char* ldsA = lds;
  char* ldsB = lds + 16384;
  int bid = blockIdx.x;
  int mt = bid / ntn, nt = bid - mt * ntn;
  int m0 = mt * 128, n0 = nt * 128;
  int tid = threadIdx.x, lane = tid & 63, wid = tid >> 6;
  int wm = wid >> 1, wn = wid & 1;
  int fr = lane & 15, fq = lane >> 4;
  f32x4 acc[4][4] = {};
  int nK = K >> 6;
  int lco = (lane & 7) * 16;
  int lrow8 = lane >> 3;
  for (int kt = 0; kt < nK; ++kt) {
    int k0 = kt << 6;
#pragma unroll
    for (int p = 0; p < 4; ++p) {
      int chunk = wid * 4 + p;
      int row = chunk * 8 + lrow8;
      int colb = lco ^ ((row & 7) << 4);
      int ar = m0 + row; if (ar >= M) ar = M - 1;
      gload_lds16((const char*)(A + (size_t)ar * K + k0) + colb, ldsA + chunk * 1024);
      gload_lds16((const char*)(Bt + (size_t)(n0 + row) * K + k0) + colb, ldsB + chunk * 1024);
    }
    __syncthreads();
    bf16x8 af[4][2], bfr[4][2];
#pragma unroll
    for (int mi = 0; mi < 4; ++mi) {
      int r = wm * 64 + mi * 16 + fr;
#pragma unroll
      for (int kk = 0; kk < 2; ++kk)
        af[mi][kk] = *(const bf16x8*)(ldsA + swz128(r * 128 + kk * 64 + fq * 16));
    }
#pragma unroll
    for (int ni = 0; ni < 4; ++ni) {
      int r = wn * 64 + ni * 16 + fr;
#pragma unroll
      for (int kk = 0; kk < 2; ++kk)
        bfr[ni][kk] = *(const bf16x8*)(ldsB + swz128(r * 128 + kk * 64 + fq * 16));
    }
#pragma unroll
    for (int mi = 0; mi < 4; ++mi)
#pragma unroll
      for (int ni = 0; ni < 4; ++ni) {
        acc[mi][ni] = MFMA16x16(af[mi][0], bfr[ni][0], acc[mi][ni]);
        acc[mi][ni] = MFMA16x16(af[mi][1], bfr[ni][1], acc[mi][ni]);
      }
    __syncthreads();
  }
#pragma unroll
  for (int mi = 0; mi < 4; ++mi) {
#pragma unroll
    for (int j = 0; j < 4; ++j) {
      int r = m0 + wm * 64 + mi * 16 + fq * 4 + j;
      if (r >= M) continue;
#pragma unroll
      for (int ni = 0; ni < 4; ++ni) {
        int c = n0 + wn * 64 + ni * 16 + fr;
        float v = acc[mi][ni][j];
        if (MODE == 0) {
          ((unsigned short*)Cout)[(size_t)r * Nn + c] = f2bf(silu_f(v));
        } else {
          ((float*)Cout)[(size_t)r * Nn + c] = v + bias[c] + xres[(size_t)r * 512 + c];
        }
      }
    }
  }
}

// ---------- V^T prestage: vT[b][h][d=64][n=1024] bf16 ----------
// lane = d; read 8 coalesced 128B rows of the head slice, pack, 16B write per lane.
__global__ __launch_bounds__(256) void k_vT(const unsigned short* __restrict__ mm,
                                            const int* __restrict__ offs,
                                            unsigned short* __restrict__ vT) {
  int bh = blockIdx.x; int b = bh >> 3, h = bh & 7;
  int off = offs[b], len = offs[b + 1] - off;
  int lane = threadIdx.x & 63, w = threadIdx.x >> 6;
  const unsigned short* vp = mm + (size_t)off * 2048 + 512 + h * 64 + lane;
  unsigned short* vt = vT + ((size_t)bh * 64 + lane) * 1024;
  int nc = ((len + 63) & ~63) >> 3;  // zero-fill padding up to 64-multiple (attn reads it)
  for (int c = w; c < nc; c += 4) {
    int s8 = c << 3;
    unsigned short r[8];
#pragma unroll
    for (int j = 0; j < 8; ++j)
      r[j] = (s8 + j < len) ? vp[(size_t)(s8 + j) * 2048] : (unsigned short)0;
    *(uint4*)(vt + s8) = *(uint4*)r;
  }
}

// ---------- jagged causal SiLU-attention, v2 ----------
// wave = 32 q-rows, 4 independent waves/block, no barriers, K/V^T direct from L2.
// mm row: [u 0..511 | v 512..1023 | q 1024..1535 | k 1536..2047], head-major 64 each
__global__ __launch_bounds__(256) void k_attn2(const unsigned short* __restrict__ mm,
                                               const unsigned short* __restrict__ vT,
                                               const int* __restrict__ offs,
                                               unsigned short* __restrict__ attnb,
                                               float inv_n) {
  __shared__ __align__(16) char sP[16384];  // per-wave 4KB: P [32 q][64 s] bf16, swz128
  int bid = blockIdx.x;
  int orig = (bid & 7) * 128 + (bid >> 3);  // bijective XCD swizzle (grid 1024 = 8*128)
  int bh = orig >> 3, grp = orig & 7;
  int b = bh >> 3, h = bh & 7;
  int off = offs[b], len = offs[b + 1] - off;
  int tid = threadIdx.x, lane = tid & 63, wid = tid >> 6;
  int qb = grp * 128 + wid * 32;
  if (qb >= len) return;  // wave-level exit: no barriers in this kernel
  int fr = lane & 15, fq = lane >> 4;
  const unsigned short* qp = mm + (size_t)off * 2048 + 1024 + h * 64;
  const unsigned short* kp = mm + (size_t)off * 2048 + 1536 + h * 64;
  const unsigned short* vtp = vT + (size_t)bh * 64 * 1024;
  bf16x8 aq[2][2];  // Q frags: row=fr (q), k=fq*8+j (+32*kk)
#pragma unroll
  for (int mi = 0; mi < 2; ++mi) {
    int qr = qb + mi * 16 + fr; if (qr >= len) qr = len - 1;
#pragma unroll
    for (int kk = 0; kk < 2; ++kk)
      aq[mi][kk] = *(const bf16x8*)(qp + (size_t)qr * 2048 + kk * 32 + fq * 8);
  }
  f32x4 accO[2][4] = {};
  char* pw = sP + wid * 4096;
  int nkt = (qb >> 6) + 1;
  for (int kt = 0; kt < nkt; ++kt) {
    int s0 = kt << 6;
    // K B-frags (shared across both mi): n=fr (s), k=fq*8+j (d)
    bf16x8 kf[4][2];
#pragma unroll
    for (int ni = 0; ni < 4; ++ni)
#pragma unroll
      for (int kk = 0; kk < 2; ++kk)
        kf[ni][kk] = *(const bf16x8*)(kp + (size_t)(s0 + ni * 16 + fr) * 2048 + kk * 32 + fq * 8);
    // QK^T -> silu/n -> causal mask -> P (wave-private LDS)
#pragma unroll
    for (int mi = 0; mi < 2; ++mi) {
      f32x4 sacc[4] = {};
#pragma unroll
      for (int ni = 0; ni < 4; ++ni) {
        sacc[ni] = MFMA16x16(aq[mi][0], kf[ni][0], sacc[ni]);
        sacc[ni] = MFMA16x16(aq[mi][1], kf[ni][1], sacc[ni]);
      }
#pragma unroll
      for (int ni = 0; ni < 4; ++ni)
#pragma unroll
        for (int j = 0; j < 4; ++j) {
          int pq = qb + mi * 16 + fq * 4 + j;
          int ps = s0 + ni * 16 + fr;
          float v = (ps <= pq) ? silu_f(sacc[ni][j]) * inv_n : 0.0f;
          *(unsigned short*)(pw + swz128((mi * 16 + fq * 4 + j) * 128 + (ni * 16 + fr) * 2)) =
              f2bf(v);
        }
    }
    // V^T B-frags direct from global: n=fr (d), k=fq*8+j (s)
    bf16x8 vf[4][2];
#pragma unroll
    for (int nd = 0; nd < 4; ++nd)
#pragma unroll
      for (int kk = 0; kk < 2; ++kk)
        vf[nd][kk] = *(const bf16x8*)(vtp + (size_t)(nd * 16 + fr) * 1024 + s0 + kk * 32 + fq * 8);
    // O += P V
#pragma unroll
    for (int mi = 0; mi < 2; ++mi) {
      bf16x8 pa0 = *(const bf16x8*)(pw + swz128((mi * 16 + fr) * 128 + fq * 16));
      bf16x8 pa1 = *(const bf16x8*)(pw + swz128((mi * 16 + fr) * 128 + 64 + fq * 16));
#pragma unroll
      for (int nd = 0; nd < 4; ++nd) {
        accO[mi][nd] = MFMA16x16(pa0, vf[nd][0], accO[mi][nd]);
        accO[mi][nd] = MFMA16x16(pa1, vf[nd][1], accO[mi][nd]);
      }
    }
  }
#pragma unroll
  for (int mi = 0; mi < 2; ++mi)
#pragma unroll
    for (int nd = 0; nd < 4; ++nd)
#pragma unroll
      for (int j = 0; j < 4; ++j) {
        int pq = qb + mi * 16 + fq * 4 + j;
        if (pq < len)
          attnb[(size_t)(off + pq) * 512 + h * 64 + nd * 16 + fr] = f2bf(accO[mi][nd][j]);
      }
}

extern "C" void kernel_launch(void* const* d_in, const int* in_sizes, int n_in,
                              void* d_out, int out_size, void* d_ws, size_t ws_size,
                              hipStream_t stream) {
  const float* x = (const float*)d_in[0];
  const int* xoff = (const int*)d_in[1];
  // d_in[2] = invalid_attn_mask (causal tril) -- applied analytically
  const float* uvqk = (const float*)d_in[3];
  const float* ow = (const float*)d_in[4];
  const float* obias = (const float*)d_in[5];

  const int D = 512;
  int T = in_sizes[0] / D;
  int B = in_sizes[1] - 1;
  int nm = 1;
  while ((long long)nm * nm < (long long)in_sizes[2]) nm <<= 1;  // mask dim (1024)

  char* w = (char*)d_ws;
  size_t p = 0;
  auto alloc = [&](size_t bytes) { size_t r = p; p += (bytes + 255) & ~(size_t)255; return r; };
  int* offs = (int*)(w + alloc(sizeof(int) * (size_t)(B + 1)));
  unsigned short* normed = (unsigned short*)(w + alloc((size_t)T * 512 * 2));
  unsigned short* mm = (unsigned short*)(w + alloc((size_t)T * 2048 * 2));
  unsigned short* attnb = (unsigned short*)(w + alloc((size_t)T * 512 * 2));
  unsigned short* oin = (unsigned short*)(w + alloc((size_t)T * 512 * 2));
  unsigned short* uvqkT = (unsigned short*)(w + alloc((size_t)2048 * 512 * 2));
  unsigned short* owb = (unsigned short*)(w + alloc((size_t)512 * 512 * 2));
  unsigned short* vT = (unsigned short*)(w + alloc((size_t)B * 8 * 64 * (size_t)nm * 2));

  k_prep_offs<<<1, 32, 0, stream>>>(xoff, offs, B + 1);
  k_conv_uvqkT<<<dim3(64, 16), 256, 0, stream>>>(uvqk, uvqkT);
  k_conv_bf16<<<1024, 256, 0, stream>>>(ow, owb, 512 * 512);
  k_ln_x<<<(T + 3) / 4, 256, 0, stream>>>(x, normed, T);
  int ntm = (T + 127) / 128;
  k_gemm_bt<0><<<ntm * 16, 256, 0, stream>>>(normed, uvqkT, (void*)mm, nullptr, nullptr,
                                             T, 2048, 512, 16);
  k_vT<<<B * 8, 256, 0, stream>>>(mm, offs, vT);
  k_attn2<<<(B * 8 * nm / 128), 256, 0, stream>>>(mm, vT, offs, attnb, 1.0f / (float)nm);
  k_ln_mul_u<<<(T + 3) / 4, 256, 0, stream>>>(attnb, mm, oin, T);
  k_gemm_bt<1><<<ntm * 4, 256, 0, stream>>>(oin, owb, d_out, obias, x, T, 512, 512, 4);
}